// Round 1
// baseline (242.971 us; speedup 1.0000x reference)
//
#include <hip/hip_runtime.h>

#define LSEQ 512
#define NB 64

// Soft-DTW wavefront: one block per batch, thread t owns DP row i = t+1.
// Anti-diagonal k = i + j runs 2..2L. Triple-buffered LDS diagonals allow a
// single __syncthreads per step:
//   pm2 = diag k-2, pm1 = diag k-1, pw = diag k (overwrites dead diag k-3).
// buf[d][r] holds R[r][d-r]. Thread t reads index t (= row i-1), writes t+1.
__global__ __launch_bounds__(512) void dtw_wavefront(
    const float* __restrict__ pred, const float* __restrict__ target,
    float* __restrict__ part) {
  const int b = blockIdx.x;
  const int t = threadIdx.x;  // DP row i = t+1

  __shared__ float buf0[LSEQ + 1];
  __shared__ float buf1[LSEQ + 1];
  __shared__ float buf2[LSEQ + 1];
  __shared__ float tg[LSEQ];

  const float p = pred[b * LSEQ + t];  // pred[b][i-1]
  tg[t] = target[b * LSEQ + t];
  buf0[t] = INFINITY;
  buf1[t] = INFINITY;
  buf2[t] = INFINITY;
  if (t == 0) {
    buf0[LSEQ] = INFINITY;
    buf1[LSEQ] = INFINITY;
    buf2[LSEQ] = INFINITY;
    buf0[0] = 0.0f;  // R[0][0] on diagonal 0
  }
  __syncthreads();

  float* pm2 = buf0;  // diag k-2
  float* pm1 = buf1;  // diag k-1
  float* pw = buf2;   // diag k (dead k-3 values)

  float r_left = INFINITY;  // R[i][0] boundary
  float vfinal = 0.0f;

  const float inv_g = 10.0f;  // 1/gamma
  const float g = 0.1f;

  for (int k = 2; k <= 2 * LSEQ; ++k) {
    const int j = k - (t + 1);
    const float r0 = pm2[t];  // R[i-1][j-1]
    const float r1 = pm1[t];  // R[i-1][j]
    if (j >= 1 && j <= LSEQ) {
      const float diff = p - tg[j - 1];
      const float d = diff * diff;
      const float m = fminf(fminf(r0, r1), r_left);
      // stable softmin: every interior cell has a finite predecessor -> m finite;
      // (m - inf) * inv_g = -inf -> __expf gives 0, no NaN.
      const float s = __expf((m - r0) * inv_g) + __expf((m - r1) * inv_g) +
                      __expf((m - r_left) * inv_g);
      const float v = d + m - g * __logf(s);
      pw[t + 1] = v;
      r_left = v;
      vfinal = v;
    }
    if (t == 0) pw[0] = INFINITY;  // R[0][k] boundary for future reads
    float* tmp = pm2;
    pm2 = pm1;
    pm1 = pw;
    pw = tmp;
    __syncthreads();
  }

  if (t == LSEQ - 1) part[b] = vfinal;  // R[L][L] at k = 2L
}

__global__ void dtw_reduce(const float* __restrict__ part,
                           float* __restrict__ out) {
  float v = part[threadIdx.x];
#pragma unroll
  for (int o = 32; o > 0; o >>= 1) v += __shfl_down(v, o);
  if (threadIdx.x == 0) out[0] = v * (1.0f / NB);
}

extern "C" void kernel_launch(void* const* d_in, const int* in_sizes, int n_in,
                              void* d_out, int out_size, void* d_ws,
                              size_t ws_size, hipStream_t stream) {
  const float* pred = (const float*)d_in[0];
  const float* target = (const float*)d_in[1];
  float* part = (float*)d_ws;  // 64 floats of scratch

  dtw_wavefront<<<NB, LSEQ, 0, stream>>>(pred, target, part);
  dtw_reduce<<<1, 64, 0, stream>>>(part, (float*)d_out);
}